// Round 7
// baseline (246.811 us; speedup 1.0000x reference)
//
#include <hip/hip_runtime.h>
#include <cstdint>
#include <cstddef>

// MSA row attention (openfold-style), bf16 MFMA pipeline v6.
// v6 = v5 with FIXED barrier semantics in the prefetch GEMMs:
//   raw __builtin_amdgcn_s_barrier() is NOT a compiler memory fence ->
//   LLVM hoisted next-tile global_load_lds above the end barrier (LDS race).
//   Fix: sched_barrier(0) + asm s_barrier with "memory" clobber.
#define S_  128
#define R_  384
#define C_  256
#define H_  8
#define D_  32
#define HD_ 256
#define M_  (S_*R_)      // 49152

#define LOG2E 1.4426950408889634f

typedef float f32x16 __attribute__((ext_vector_type(16)));
typedef short s16x8  __attribute__((ext_vector_type(8)));
typedef int   i32x4  __attribute__((ext_vector_type(4)));

__device__ __forceinline__ unsigned short f2bf(float f) {
  uint32_t u = __float_as_uint(f);
  u += 0x7fffu + ((u >> 16) & 1u);
  return (unsigned short)(u >> 16);
}
__device__ __forceinline__ float bf2f(unsigned short s) {
  return __uint_as_float(((uint32_t)s) << 16);
}
__device__ __forceinline__ uint32_t pkbf(float lo, float hi) {
  return (uint32_t)f2bf(lo) | ((uint32_t)f2bf(hi) << 16);
}
#define MFMA32(a,b,c) __builtin_amdgcn_mfma_f32_32x32x16_bf16((a),(b),(c),0,0,0)

__device__ __forceinline__ void gload16(const void* g, void* l) {
  __builtin_amdgcn_global_load_lds(
      (const __attribute__((address_space(1))) void*)g,
      (__attribute__((address_space(3))) void*)l, 16, 0, 0);
}

// Barrier that is BOTH a HW workgroup barrier and a compiler memory fence,
// WITHOUT the vmcnt(0)/lgkmcnt(0) drain __syncthreads() would emit.
__device__ __forceinline__ void barrier_fence() {
  __builtin_amdgcn_sched_barrier(0);
  asm volatile("s_barrier" ::: "memory");
  __builtin_amdgcn_sched_barrier(0);
}

// ---------------------------------------------------------------------------
// Kernel 0: weight prep — LDS-tiled transpose + cvt bf16. WT[mat][n][k].
// ---------------------------------------------------------------------------
__global__ __launch_bounds__(256) void prep_w(const float* __restrict__ wq,
    const float* __restrict__ wk, const float* __restrict__ wv,
    const float* __restrict__ wg, const float* __restrict__ wo,
    unsigned short* __restrict__ WT) {
  __shared__ unsigned short Tl[64][72];
  const int mat = blockIdx.x >> 4;
  const int t   = blockIdx.x & 15;
  const int k0  = (t >> 2) * 64, n0 = (t & 3) * 64;
  const float* W = (mat==0)?wq:(mat==1)?wk:(mat==2)?wv:(mat==3)?wg:wo;
  const int tx = threadIdx.x & 63, ty = threadIdx.x >> 6;
#pragma unroll
  for (int i = 0; i < 16; i++) {
    int kk = ty + i * 4;
    Tl[tx][kk] = f2bf(W[(size_t)(k0 + kk) * 256 + n0 + tx]);
  }
  __syncthreads();
#pragma unroll
  for (int i = 0; i < 16; i++) {
    int nn = ty + i * 4;
    WT[(size_t)mat * 65536 + (size_t)(n0 + nn) * 256 + k0 + tx] = Tl[nn][tx];
  }
}

// ---------------------------------------------------------------------------
// Kernel 1: LayerNorm over C=256, one wave per row, writes bf16.
// ---------------------------------------------------------------------------
__global__ __launch_bounds__(256) void ln_kernel(const float* __restrict__ mIn,
    const float* __restrict__ w, const float* __restrict__ b,
    unsigned short* __restrict__ x) {
  int row  = blockIdx.x * 4 + (threadIdx.x >> 6);
  int lane = threadIdx.x & 63;
  const float4 v4 = *(const float4*)(mIn + (size_t)row * C_ + lane * 4);
  float s  = v4.x + v4.y + v4.z + v4.w;
  float ss = v4.x*v4.x + v4.y*v4.y + v4.z*v4.z + v4.w*v4.w;
#pragma unroll
  for (int off = 32; off > 0; off >>= 1) {
    s  += __shfl_xor(s,  off);
    ss += __shfl_xor(ss, off);
  }
  float mu  = s * (1.0f / C_);
  float var = ss * (1.0f / C_) - mu * mu;
  float rs  = rsqrtf(var + 1e-5f);
  const float4 wv = *(const float4*)(w + lane * 4);
  const float4 bv = *(const float4*)(b + lane * 4);
  uint2 o2;
  o2.x = pkbf((v4.x - mu) * rs * wv.x + bv.x, (v4.y - mu) * rs * wv.y + bv.y);
  o2.y = pkbf((v4.z - mu) * rs * wv.z + bv.z, (v4.w - mu) * rs * wv.w + bv.w);
  *(uint2*)(x + (size_t)row * C_ + lane * 4) = o2;
}

// ---------------------------------------------------------------------------
// Kernel 2: fused QKVG projection. 64x128 tile, BK=32, double-buffered LDS,
// counted vmcnt(3) prefetch; fenced raw barriers (no drain).
// ---------------------------------------------------------------------------
__global__ __launch_bounds__(256) void proj_gemm(const unsigned short* __restrict__ X,
    const unsigned short* __restrict__ WT, const float* __restrict__ bg,
    unsigned short* __restrict__ Qo, unsigned short* __restrict__ Ko,
    unsigned short* __restrict__ Vo, unsigned short* __restrict__ Go) {
  __shared__ __align__(16) unsigned short As[2][64 * 32];
  __shared__ __align__(16) unsigned short Bs[2][128 * 32];
  const int tid = threadIdx.x;
  const int wi  = blockIdx.x >> 1;
  const int bn  = (blockIdx.x & 1) * 128;
  const int bm  = blockIdx.y * 64;
  const unsigned short* Wt = WT + (size_t)wi * 65536;
  unsigned short* O = (wi==0)?Qo:(wi==1)?Ko:(wi==2)?Vo:Go;

  const int lane = tid & 63, wid = tid >> 6;
  const int wr = (wid >> 1) * 32, wc = (wid & 1) * 64;
  const int lr = lane & 31, hi = lane >> 5;
  const int srow = lane >> 2, scol = (lane & 3) * 8;

  const unsigned short* Xs = X  + (size_t)(bm + wid*16 + srow) * 256 + scol;
  const unsigned short* W0 = Wt + (size_t)(bn + wid*32 + srow) * 256 + scol;
  const unsigned short* W1 = W0 + 16 * 256;

#define PSTAGE(buf, k0) do {                         \
    gload16(Xs + (k0), &As[buf][wid * 512]);          \
    gload16(W0 + (k0), &Bs[buf][(wid*32) * 32]);      \
    gload16(W1 + (k0), &Bs[buf][(wid*32 + 16) * 32]); \
  } while (0)

  f32x16 acc0, acc1;
#pragma unroll
  for (int r = 0; r < 16; r++) { acc0[r] = 0.f; acc1[r] = 0.f; }

  PSTAGE(0, 0);
#pragma unroll
  for (int t = 0; t < 8; ++t) {
    if (t < 7) {
      PSTAGE((t + 1) & 1, (t + 1) * 32);
      asm volatile("s_waitcnt vmcnt(3)" ::: "memory");   // tile t done, t+1 in flight
    } else {
      asm volatile("s_waitcnt vmcnt(0)" ::: "memory");
    }
    barrier_fence();
    const unsigned short* Ab = As[t & 1];
    const unsigned short* Bb = Bs[t & 1];
#pragma unroll
    for (int kh = 0; kh < 2; kh++) {
      s16x8 a0 = *(const s16x8*)&Ab[(wr + lr) * 32      + kh*16 + 8*hi];
      s16x8 b0 = *(const s16x8*)&Bb[(wc + lr) * 32      + kh*16 + 8*hi];
      s16x8 b1 = *(const s16x8*)&Bb[(wc + 32 + lr) * 32 + kh*16 + 8*hi];
      acc0 = MFMA32(a0, b0, acc0);
      acc1 = MFMA32(a0, b1, acc1);
    }
    barrier_fence();
  }
#undef PSTAGE

  const float qs2 = 0.17677669529663687f * LOG2E;
#pragma unroll
  for (int ns = 0; ns < 2; ns++) {
    const f32x16& a = ns ? acc1 : acc0;
    int colg = bn + wc + ns*32 + lr;
    float bgv = (wi == 3) ? bg[colg] : 0.f;
#pragma unroll
    for (int r = 0; r < 16; r++) {
      float v = a[r];
      if (wi == 0) v *= qs2;
      if (wi == 3) v = 1.0f / (1.0f + __expf(-(v + bgv)));
      int row = bm + wr + (r & 3) + 8*(r >> 2) + 4*hi;
      O[(size_t)row * 256 + colg] = f2bf(v);
    }
  }
}

// ---------------------------------------------------------------------------
// Kernel 3: MFMA flash attention per (s,h). 12 waves x 1 q-strip of 32.
// (unchanged from v4)
// ---------------------------------------------------------------------------
__global__ __launch_bounds__(768, 6) void attn_kernel(const unsigned short* __restrict__ Qb,
    const unsigned short* __restrict__ Kb, const unsigned short* __restrict__ Vb,
    const unsigned short* __restrict__ Gb, const float* __restrict__ mask,
    unsigned short* __restrict__ Ob) {
  __shared__ unsigned short Kl[384][40];   // [k-row][d], 80B stride
  __shared__ unsigned short VT[32][392];   // [d][k-row]
  __shared__ float mb[384];
  __shared__ float sAl[12][32];

  const int h = blockIdx.x, s = blockIdx.y;
  const int tid = threadIdx.x;
  const int wid = tid >> 6, lane = tid & 63;
  const int lr = lane & 31, hi = lane >> 5;

  if (tid < 384) {
    const unsigned short* ksrc = Kb + ((size_t)(s*R_ + tid)) * 256 + h*32;
    uint4 k0 = *(const uint4*)ksrc;
    uint4 k1 = *(const uint4*)(ksrc + 8);
    uint4 k2 = *(const uint4*)(ksrc + 16);
    uint4 k3 = *(const uint4*)(ksrc + 24);
    *(uint4*)&Kl[tid][0]  = k0;
    *(uint4*)&Kl[tid][8]  = k1;
    *(uint4*)&Kl[tid][16] = k2;
    *(uint4*)&Kl[tid][24] = k3;
    mb[tid] = (1e9f * LOG2E) * (mask[s * R_ + tid] - 1.0f);
  } else {
    const int r = tid - 384;
    const unsigned short* vsrc = Vb + ((size_t)(s*R_ + r)) * 256 + h*32;
    unsigned short tmp[32];
    *(uint4*)(tmp)      = *(const uint4*)vsrc;
    *(uint4*)(tmp + 8)  = *(const uint4*)(vsrc + 8);
    *(uint4*)(tmp + 16) = *(const uint4*)(vsrc + 16);
    *(uint4*)(tmp + 24) = *(const uint4*)(vsrc + 24);
#pragma unroll
    for (int j = 0; j < 32; j++) VT[j][r] = tmp[j];
  }

  const int q0 = wid * 32;
  const unsigned short* qsrc = Qb + ((size_t)(s*R_ + q0 + lr)) * 256 + h*32;
  s16x8 bq0 = *(const s16x8*)(qsrc + 8*hi);
  s16x8 bq1 = *(const s16x8*)(qsrc + 16 + 8*hi);

  f32x16 of;
#pragma unroll
  for (int r = 0; r < 16; r++) of[r] = 0.f;
  float mrun = -1e30f, lsum = 0.f;

  __syncthreads();

  for (int kt = 0; kt < 12; kt++) {
    s16x8 ak0 = *(const s16x8*)&Kl[kt*32 + lr][8*hi];
    s16x8 ak1 = *(const s16x8*)&Kl[kt*32 + lr][16 + 8*hi];
    s16x8 bv0 = *(const s16x8*)&VT[lr][kt*32 + 8*hi];
    s16x8 bv1 = *(const s16x8*)&VT[lr][kt*32 + 16 + 8*hi];

    f32x16 p;
#pragma unroll
    for (int r = 0; r < 16; r++) p[r] = mb[kt*32 + (r & 3) + 8*(r >> 2) + 4*hi];
    __builtin_amdgcn_s_setprio(1);
    p = MFMA32(ak0, bq0, p);
    p = MFMA32(ak1, bq1, p);
    __builtin_amdgcn_s_setprio(0);

    float m01 = fmaxf(fmaxf(p[0], p[1]), fmaxf(p[2], p[3]));
    float m23 = fmaxf(fmaxf(p[4], p[5]), fmaxf(p[6], p[7]));
    float m45 = fmaxf(fmaxf(p[8], p[9]), fmaxf(p[10], p[11]));
    float m67 = fmaxf(fmaxf(p[12], p[13]), fmaxf(p[14], p[15]));
    float pm = fmaxf(fmaxf(m01, m23), fmaxf(m45, m67));
    pm = fmaxf(pm, __shfl_xor(pm, 32));
    if (!__all(pm <= mrun + 11.54f)) {          // defer-max (log2 units)
      float nm = fmaxf(mrun, pm);
      float al = __builtin_amdgcn_exp2f(mrun - nm);
      mrun = nm;
      lsum *= al;
      if (hi == 0) sAl[wid][lr] = al;
#pragma unroll
      for (int r = 0; r < 16; r++)
        of[r] *= sAl[wid][(r & 3) + 8*(r >> 2) + 4*hi];
    }
    float ls = 0.f;
#pragma unroll
    for (int r = 0; r < 16; r++) {
      p[r] = __builtin_amdgcn_exp2f(p[r] - mrun);
      ls += p[r];
    }
    lsum += ls;

    uint32_t w0, w1, w2, w3, w4, w5, w6, w7;
    asm("v_cvt_pk_bf16_f32 %0, %1, %2" : "=v"(w0) : "v"(p[0]),  "v"(p[1]));
    asm("v_cvt_pk_bf16_f32 %0, %1, %2" : "=v"(w1) : "v"(p[2]),  "v"(p[3]));
    asm("v_cvt_pk_bf16_f32 %0, %1, %2" : "=v"(w2) : "v"(p[4]),  "v"(p[5]));
    asm("v_cvt_pk_bf16_f32 %0, %1, %2" : "=v"(w3) : "v"(p[6]),  "v"(p[7]));
    asm("v_cvt_pk_bf16_f32 %0, %1, %2" : "=v"(w4) : "v"(p[8]),  "v"(p[9]));
    asm("v_cvt_pk_bf16_f32 %0, %1, %2" : "=v"(w5) : "v"(p[10]), "v"(p[11]));
    asm("v_cvt_pk_bf16_f32 %0, %1, %2" : "=v"(w6) : "v"(p[12]), "v"(p[13]));
    asm("v_cvt_pk_bf16_f32 %0, %1, %2" : "=v"(w7) : "v"(p[14]), "v"(p[15]));
    asm volatile("v_permlane32_swap_b32 %0, %1" : "+v"(w0), "+v"(w2));
    asm volatile("v_permlane32_swap_b32 %0, %1" : "+v"(w1), "+v"(w3));
    asm volatile("v_permlane32_swap_b32 %0, %1" : "+v"(w4), "+v"(w6));
    asm volatile("v_permlane32_swap_b32 %0, %1" : "+v"(w5), "+v"(w7));
    i32x4 pa0i = {(int)w0, (int)w1, (int)w2, (int)w3};
    i32x4 pa1i = {(int)w4, (int)w5, (int)w6, (int)w7};
    __builtin_amdgcn_s_setprio(1);
    of = MFMA32(__builtin_bit_cast(s16x8, pa0i), bv0, of);
    of = MFMA32(__builtin_bit_cast(s16x8, pa1i), bv1, of);
    __builtin_amdgcn_s_setprio(0);
  }

  float lt = lsum + __shfl_xor(lsum, 32);
  float inv = 1.0f / lt;
  if (hi == 0) sAl[wid][lr] = inv;
#pragma unroll
  for (int r = 0; r < 16; r++) {
    int crow = (r & 3) + 8*(r >> 2) + 4*hi;
    float iv = sAl[wid][crow];
    size_t off = ((size_t)(s*R_ + q0 + crow)) * 256 + h*32 + lr;
    float gv = bf2f(Gb[off]);
    Ob[off] = f2bf(of[r] * iv * gv);
  }
}

// ---------------------------------------------------------------------------
// Kernel 4: output GEMM. 64x128 tile, double-buffered + counted-vmcnt
// prefetch, fenced barriers. Out fp32 + bo.
// ---------------------------------------------------------------------------
__global__ __launch_bounds__(256) void out_gemm(const unsigned short* __restrict__ Ob,
    const unsigned short* __restrict__ WT, const float* __restrict__ bo,
    float* __restrict__ Out) {
  __shared__ __align__(16) unsigned short As[2][64 * 32];
  __shared__ __align__(16) unsigned short Bs[2][128 * 32];
  const unsigned short* Wt = WT + 4 * 65536;
  const int tid = threadIdx.x;
  const int bn = blockIdx.x * 128;
  const int bm = blockIdx.y * 64;
  const int lane = tid & 63, wid = tid >> 6;
  const int wr = (wid >> 1) * 32, wc = (wid & 1) * 64;
  const int lr = lane & 31, hi = lane >> 5;
  const int srow = lane >> 2, scol = (lane & 3) * 8;

  const unsigned short* Asrc = Ob + (size_t)(bm + wid*16 + srow) * 256 + scol;
  const unsigned short* W0   = Wt + (size_t)(bn + wid*32 + srow) * 256 + scol;
  const unsigned short* W1   = W0 + 16 * 256;

#define OSTAGE(buf, k0) do {                          \
    gload16(Asrc + (k0), &As[buf][wid * 512]);         \
    gload16(W0   + (k0), &Bs[buf][(wid*32) * 32]);     \
    gload16(W1   + (k0), &Bs[buf][(wid*32 + 16) * 32]);\
  } while (0)

  f32x16 acc0, acc1;
#pragma unroll
  for (int r = 0; r < 16; r++) { acc0[r] = 0.f; acc1[r] = 0.f; }

  OSTAGE(0, 0);
#pragma unroll
  for (int t = 0; t < 8; ++t) {
    if (t < 7) {
      OSTAGE((t + 1) & 1, (t + 1) * 32);
      asm volatile("s_waitcnt vmcnt(3)" ::: "memory");
    } else {
      asm volatile("s_waitcnt vmcnt(0)" ::: "memory");
    }
    barrier_fence();
    const unsigned short* Ab = As[t & 1];
    const unsigned short* Bb = Bs[t & 1];
#pragma unroll
    for (int kh = 0; kh < 2; kh++) {
      s16x8 a0 = *(const s16x8*)&Ab[(wr + lr) * 32      + kh*16 + 8*hi];
      s16x8 b0 = *(const s16x8*)&Bb[(wc + lr) * 32      + kh*16 + 8*hi];
      s16x8 b1 = *(const s16x8*)&Bb[(wc + 32 + lr) * 32 + kh*16 + 8*hi];
      acc0 = MFMA32(a0, b0, acc0);
      acc1 = MFMA32(a0, b1, acc1);
    }
    barrier_fence();
  }
#undef OSTAGE

#pragma unroll
  for (int ns = 0; ns < 2; ns++) {
    const f32x16& a = ns ? acc1 : acc0;
    int colg = bn + wc + ns*32 + lr;
    float bov = bo[colg];
#pragma unroll
    for (int r = 0; r < 16; r++) {
      int row = bm + wr + (r & 3) + 8*(r >> 2) + 4*hi;
      Out[(size_t)row * 256 + colg] = a[r] + bov;
    }
  }
}

// ---------------------------------------------------------------------------
// Host launcher
// ---------------------------------------------------------------------------
extern "C" void kernel_launch(void* const* d_in, const int* in_sizes, int n_in,
                              void* d_out, int out_size, void* d_ws, size_t ws_size,
                              hipStream_t stream) {
  const float* m    = (const float*)d_in[0];
  const float* mask = (const float*)d_in[1];
  const float* ln_w = (const float*)d_in[2];
  const float* ln_b = (const float*)d_in[3];
  const float* wq   = (const float*)d_in[4];
  const float* wk   = (const float*)d_in[5];
  const float* wv   = (const float*)d_in[6];
  const float* wg   = (const float*)d_in[7];
  const float* bg   = (const float*)d_in[8];
  const float* wo   = (const float*)d_in[9];
  const float* bo   = (const float*)d_in[10];
  float* out = (float*)d_out;

  unsigned short* ws = (unsigned short*)d_ws;
  const size_t SZ = (size_t)M_ * 256;
  unsigned short* xbf = ws;
  unsigned short* qb  = ws + 1 * SZ;
  unsigned short* kb  = ws + 2 * SZ;
  unsigned short* vb  = ws + 3 * SZ;
  unsigned short* gb  = ws + 4 * SZ;
  unsigned short* ob  = ws + 5 * SZ;
  unsigned short* WT  = ws + 6 * SZ;

  prep_w<<<80, 256, 0, stream>>>(wq, wk, wv, wg, wo, WT);
  ln_kernel<<<M_ / 4, 256, 0, stream>>>(m, ln_w, ln_b, xbf);
  proj_gemm<<<dim3(8, M_ / 64), 256, 0, stream>>>(xbf, WT, bg, qb, kb, vb, gb);
  attn_kernel<<<dim3(H_, S_), 768, 0, stream>>>(qb, kb, vb, gb, mask, ob);
  out_gemm<<<dim3(2, M_ / 64), 256, 0, stream>>>(ob, WT, bo, out);
}

// Round 12
// 230.434 us; speedup vs baseline: 1.0711x; 1.0711x over previous
//
#include <hip/hip_runtime.h>
#include <cstdint>
#include <cstddef>

// MSA row attention (openfold-style), bf16 MFMA pipeline v7.
// v7: proj/out reverted to v3-proven 128^2 m97 structure (the v4 64x128 shrink
// was the regression); XCD-bijective block swizzle for X-tile L2 reuse;
// prep_w+ln merged into one launch. attn unchanged from v4/v6.
#define S_  128
#define R_  384
#define C_  256
#define H_  8
#define D_  32
#define HD_ 256
#define M_  (S_*R_)      // 49152

#define LOG2E 1.4426950408889634f

typedef float f32x16 __attribute__((ext_vector_type(16)));
typedef short s16x8  __attribute__((ext_vector_type(8)));
typedef int   i32x4  __attribute__((ext_vector_type(4)));

__device__ __forceinline__ unsigned short f2bf(float f) {
  uint32_t u = __float_as_uint(f);
  u += 0x7fffu + ((u >> 16) & 1u);
  return (unsigned short)(u >> 16);
}
__device__ __forceinline__ float bf2f(unsigned short s) {
  return __uint_as_float(((uint32_t)s) << 16);
}
__device__ __forceinline__ uint32_t pkbf(float lo, float hi) {
  return (uint32_t)f2bf(lo) | ((uint32_t)f2bf(hi) << 16);
}
#define MFMA32(a,b,c) __builtin_amdgcn_mfma_f32_32x32x16_bf16((a),(b),(c),0,0,0)

__device__ __forceinline__ void gload16(const void* g, void* l) {
  __builtin_amdgcn_global_load_lds(
      (const __attribute__((address_space(1))) void*)g,
      (__attribute__((address_space(3))) void*)l, 16, 0, 0);
}

// ---------------------------------------------------------------------------
// Kernel 0: fused weight-prep (transpose+bf16, blocks [0,80)) and LayerNorm
// (blocks [80, 80+12288)). Independent outputs; merged to cut a launch gap.
// ---------------------------------------------------------------------------
__global__ __launch_bounds__(256) void prep_ln(const float* __restrict__ wq,
    const float* __restrict__ wk, const float* __restrict__ wv,
    const float* __restrict__ wg, const float* __restrict__ wo,
    const float* __restrict__ mIn, const float* __restrict__ lw,
    const float* __restrict__ lb,
    unsigned short* __restrict__ WT, unsigned short* __restrict__ x) {
  __shared__ unsigned short Tl[64][72];
  if (blockIdx.x < 80) {
    const int mat = blockIdx.x >> 4;
    const int t   = blockIdx.x & 15;
    const int k0  = (t >> 2) * 64, n0 = (t & 3) * 64;
    const float* W = (mat==0)?wq:(mat==1)?wk:(mat==2)?wv:(mat==3)?wg:wo;
    const int tx = threadIdx.x & 63, ty = threadIdx.x >> 6;
#pragma unroll
    for (int i = 0; i < 16; i++) {
      int kk = ty + i * 4;
      Tl[tx][kk] = f2bf(W[(size_t)(k0 + kk) * 256 + n0 + tx]);
    }
    __syncthreads();
#pragma unroll
    for (int i = 0; i < 16; i++) {
      int nn = ty + i * 4;
      WT[(size_t)mat * 65536 + (size_t)(n0 + nn) * 256 + k0 + tx] = Tl[nn][tx];
    }
  } else {
    int row  = (blockIdx.x - 80) * 4 + (threadIdx.x >> 6);
    int lane = threadIdx.x & 63;
    const float4 v4 = *(const float4*)(mIn + (size_t)row * C_ + lane * 4);
    float s  = v4.x + v4.y + v4.z + v4.w;
    float ss = v4.x*v4.x + v4.y*v4.y + v4.z*v4.z + v4.w*v4.w;
#pragma unroll
    for (int off = 32; off > 0; off >>= 1) {
      s  += __shfl_xor(s,  off);
      ss += __shfl_xor(ss, off);
    }
    float mu  = s * (1.0f / C_);
    float var = ss * (1.0f / C_) - mu * mu;
    float rs  = rsqrtf(var + 1e-5f);
    const float4 wv4 = *(const float4*)(lw + lane * 4);
    const float4 bv4 = *(const float4*)(lb + lane * 4);
    uint2 o2;
    o2.x = pkbf((v4.x - mu) * rs * wv4.x + bv4.x, (v4.y - mu) * rs * wv4.y + bv4.y);
    o2.y = pkbf((v4.z - mu) * rs * wv4.z + bv4.z, (v4.w - mu) * rs * wv4.w + bv4.w);
    *(uint2*)(x + (size_t)row * C_ + lane * 4) = o2;
  }
}

// ---------------------------------------------------------------------------
// Kernel 2: fused QKVG projection. v3-proven m97 structure: 128x128 tile,
// BK=32, global_load_lds x16, linear LDS, vmcnt(0)+__syncthreads.
// 1D grid of 3072, XCD-bijective swizzle so the 8 weight-blocks sharing an
// X m-tile run contiguously on ONE XCD (X fetched ~once per tile).
// ---------------------------------------------------------------------------
__global__ __launch_bounds__(256) void proj_gemm(const unsigned short* __restrict__ X,
    const unsigned short* __restrict__ WT, const float* __restrict__ bg,
    unsigned short* __restrict__ Qo, unsigned short* __restrict__ Ko,
    unsigned short* __restrict__ Vo, unsigned short* __restrict__ Go) {
  __shared__ __align__(16) unsigned short As[128 * 32];
  __shared__ __align__(16) unsigned short Bs[128 * 32];
  // swizzle: 3072 blocks, 8 XCDs, chunk=384. sbid = xcd*384 + pos.
  const int bid  = blockIdx.x;
  const int sbid = (bid & 7) * 384 + (bid >> 3);
  const int wsel = sbid & 7;          // {wi, n-half} fastest within chunk
  const int bm   = (sbid >> 3) * 128;
  const int wi   = wsel >> 1;
  const int bn   = (wsel & 1) * 128;
  const unsigned short* Wt = WT + (size_t)wi * 65536;
  unsigned short* O = (wi==0)?Qo:(wi==1)?Ko:(wi==2)?Vo:Go;

  const int tid = threadIdx.x;
  const int lane = tid & 63, wid = tid >> 6;
  const int wm = (wid >> 1) * 64, wn = (wid & 1) * 64;
  const int lr = lane & 31, hi = lane >> 5;
  const int srow = lane >> 2, scol = (lane & 3) * 8;

  f32x16 acc[2][2];
#pragma unroll
  for (int i = 0; i < 2; i++)
#pragma unroll
    for (int j = 0; j < 2; j++)
#pragma unroll
      for (int r = 0; r < 16; r++) acc[i][j][r] = 0.f;

  for (int k0 = 0; k0 < 256; k0 += 32) {
#pragma unroll
    for (int i = 0; i < 2; i++) {
      const int rbase = wid * 32 + i * 16;
      gload16(X  + (size_t)(bm + rbase + srow) * 256 + k0 + scol, &As[rbase * 32]);
      gload16(Wt + (size_t)(bn + rbase + srow) * 256 + k0 + scol, &Bs[rbase * 32]);
    }
    asm volatile("s_waitcnt vmcnt(0)" ::: "memory");
    __syncthreads();
#pragma unroll
    for (int kh = 0; kh < 2; kh++) {
      s16x8 a0 = *(const s16x8*)&As[(wm + lr) * 32      + kh*16 + 8*hi];
      s16x8 a1 = *(const s16x8*)&As[(wm + 32 + lr) * 32 + kh*16 + 8*hi];
      s16x8 b0 = *(const s16x8*)&Bs[(wn + lr) * 32      + kh*16 + 8*hi];
      s16x8 b1 = *(const s16x8*)&Bs[(wn + 32 + lr) * 32 + kh*16 + 8*hi];
      acc[0][0] = MFMA32(a0, b0, acc[0][0]);
      acc[0][1] = MFMA32(a0, b1, acc[0][1]);
      acc[1][0] = MFMA32(a1, b0, acc[1][0]);
      acc[1][1] = MFMA32(a1, b1, acc[1][1]);
    }
    __syncthreads();
  }

  const float qs2 = 0.17677669529663687f * LOG2E;   // D^-0.5 * log2e
#pragma unroll
  for (int ms = 0; ms < 2; ms++) {
#pragma unroll
    for (int ns = 0; ns < 2; ns++) {
      int colg = bn + wn + ns*32 + lr;
      float bgv = (wi == 3) ? bg[colg] : 0.f;
#pragma unroll
      for (int r = 0; r < 16; r++) {
        float v = acc[ms][ns][r];
        if (wi == 0) v *= qs2;
        if (wi == 3) v = 1.0f / (1.0f + __expf(-(v + bgv)));
        int row = bm + wm + ms*32 + (r & 3) + 8*(r >> 2) + 4*hi;
        O[(size_t)row * 256 + colg] = f2bf(v);
      }
    }
  }
}

// ---------------------------------------------------------------------------
// Kernel 3: MFMA flash attention per (s,h). 12 waves x 1 q-strip of 32.
// (unchanged from v4/v6 — measured 2x win held)
// ---------------------------------------------------------------------------
__global__ __launch_bounds__(768, 6) void attn_kernel(const unsigned short* __restrict__ Qb,
    const unsigned short* __restrict__ Kb, const unsigned short* __restrict__ Vb,
    const unsigned short* __restrict__ Gb, const float* __restrict__ mask,
    unsigned short* __restrict__ Ob) {
  __shared__ unsigned short Kl[384][40];   // [k-row][d], 80B stride
  __shared__ unsigned short VT[32][392];   // [d][k-row]
  __shared__ float mb[384];
  __shared__ float sAl[12][32];

  const int h = blockIdx.x, s = blockIdx.y;
  const int tid = threadIdx.x;
  const int wid = tid >> 6, lane = tid & 63;
  const int lr = lane & 31, hi = lane >> 5;

  if (tid < 384) {
    const unsigned short* ksrc = Kb + ((size_t)(s*R_ + tid)) * 256 + h*32;
    uint4 k0 = *(const uint4*)ksrc;
    uint4 k1 = *(const uint4*)(ksrc + 8);
    uint4 k2 = *(const uint4*)(ksrc + 16);
    uint4 k3 = *(const uint4*)(ksrc + 24);
    *(uint4*)&Kl[tid][0]  = k0;
    *(uint4*)&Kl[tid][8]  = k1;
    *(uint4*)&Kl[tid][16] = k2;
    *(uint4*)&Kl[tid][24] = k3;
    mb[tid] = (1e9f * LOG2E) * (mask[s * R_ + tid] - 1.0f);
  } else {
    const int r = tid - 384;
    const unsigned short* vsrc = Vb + ((size_t)(s*R_ + r)) * 256 + h*32;
    unsigned short tmp[32];
    *(uint4*)(tmp)      = *(const uint4*)vsrc;
    *(uint4*)(tmp + 8)  = *(const uint4*)(vsrc + 8);
    *(uint4*)(tmp + 16) = *(const uint4*)(vsrc + 16);
    *(uint4*)(tmp + 24) = *(const uint4*)(vsrc + 24);
#pragma unroll
    for (int j = 0; j < 32; j++) VT[j][r] = tmp[j];
  }

  const int q0 = wid * 32;
  const unsigned short* qsrc = Qb + ((size_t)(s*R_ + q0 + lr)) * 256 + h*32;
  s16x8 bq0 = *(const s16x8*)(qsrc + 8*hi);
  s16x8 bq1 = *(const s16x8*)(qsrc + 16 + 8*hi);

  f32x16 of;
#pragma unroll
  for (int r = 0; r < 16; r++) of[r] = 0.f;
  float mrun = -1e30f, lsum = 0.f;

  __syncthreads();

  for (int kt = 0; kt < 12; kt++) {
    s16x8 ak0 = *(const s16x8*)&Kl[kt*32 + lr][8*hi];
    s16x8 ak1 = *(const s16x8*)&Kl[kt*32 + lr][16 + 8*hi];
    s16x8 bv0 = *(const s16x8*)&VT[lr][kt*32 + 8*hi];
    s16x8 bv1 = *(const s16x8*)&VT[lr][kt*32 + 16 + 8*hi];

    f32x16 p;
#pragma unroll
    for (int r = 0; r < 16; r++) p[r] = mb[kt*32 + (r & 3) + 8*(r >> 2) + 4*hi];
    __builtin_amdgcn_s_setprio(1);
    p = MFMA32(ak0, bq0, p);
    p = MFMA32(ak1, bq1, p);
    __builtin_amdgcn_s_setprio(0);

    float m01 = fmaxf(fmaxf(p[0], p[1]), fmaxf(p[2], p[3]));
    float m23 = fmaxf(fmaxf(p[4], p[5]), fmaxf(p[6], p[7]));
    float m45 = fmaxf(fmaxf(p[8], p[9]), fmaxf(p[10], p[11]));
    float m67 = fmaxf(fmaxf(p[12], p[13]), fmaxf(p[14], p[15]));
    float pm = fmaxf(fmaxf(m01, m23), fmaxf(m45, m67));
    pm = fmaxf(pm, __shfl_xor(pm, 32));
    if (!__all(pm <= mrun + 11.54f)) {          // defer-max (log2 units)
      float nm = fmaxf(mrun, pm);
      float al = __builtin_amdgcn_exp2f(mrun - nm);
      mrun = nm;
      lsum *= al;
      if (hi == 0) sAl[wid][lr] = al;
#pragma unroll
      for (int r = 0; r < 16; r++)
        of[r] *= sAl[wid][(r & 3) + 8*(r >> 2) + 4*hi];
    }
    float ls = 0.f;
#pragma unroll
    for (int r = 0; r < 16; r++) {
      p[r] = __builtin_amdgcn_exp2f(p[r] - mrun);
      ls += p[r];
    }
    lsum += ls;

    uint32_t w0, w1, w2, w3, w4, w5, w6, w7;
    asm("v_cvt_pk_bf16_f32 %0, %1, %2" : "=v"(w0) : "v"(p[0]),  "v"(p[1]));
    asm("v_cvt_pk_bf16_f32 %0, %1, %2" : "=v"(w1) : "v"(p[2]),  "v"(p[3]));
    asm("v_cvt_pk_bf16_f32 %0, %1, %2" : "=v"(w2) : "v"(p[4]),  "v"(p[5]));
    asm("v_cvt_pk_bf16_f32 %0, %1, %2" : "=v"(w3) : "v"(p[6]),  "v"(p[7]));
    asm("v_cvt_pk_bf16_f32 %0, %1, %2" : "=v"(w4) : "v"(p[8]),  "v"(p[9]));
    asm("v_cvt_pk_bf16_f32 %0, %1, %2" : "=v"(w5) : "v"(p[10]), "v"(p[11]));
    asm("v_cvt_pk_bf16_f32 %0, %1, %2" : "=v"(w6) : "v"(p[12]), "v"(p[13]));
    asm("v_cvt_pk_bf16_f32 %0, %1, %2" : "=v"(w7) : "v"(p[14]), "v"(p[15]));
    asm volatile("v_permlane32_swap_b32 %0, %1" : "+v"(w0), "+v"(w2));
    asm volatile("v_permlane32_swap_b32 %0, %1" : "+v"(w1), "+v"(w3));
    asm volatile("v_permlane32_swap_b32 %0, %1" : "+v"(w4), "+v"(w6));
    asm volatile("v_permlane32_swap_b32 %0, %1" : "+v"(w5), "+v"(w7));
    i32x4 pa0i = {(int)w0, (int)w1, (int)w2, (int)w3};
    i32x4 pa1i = {(int)w4, (int)w5, (int)w6, (int)w7};
    __builtin_amdgcn_s_setprio(1);
    of = MFMA32(__builtin_bit_cast(s16x8, pa0i), bv0, of);
    of = MFMA32(__builtin_bit_cast(s16x8, pa1i), bv1, of);
    __builtin_amdgcn_s_setprio(0);
  }

  float lt = lsum + __shfl_xor(lsum, 32);
  float inv = 1.0f / lt;
  if (hi == 0) sAl[wid][lr] = inv;
#pragma unroll
  for (int r = 0; r < 16; r++) {
    int crow = (r & 3) + 8*(r >> 2) + 4*hi;
    float iv = sAl[wid][crow];
    size_t off = ((size_t)(s*R_ + q0 + crow)) * 256 + h*32 + lr;
    float gv = bf2f(Gb[off]);
    Ob[off] = f2bf(of[r] * iv * gv);
  }
}

// ---------------------------------------------------------------------------
// Kernel 4: output GEMM. 128x128 m97 structure, A = gated O (pure copy),
// B = wo^T. XCD-bijective swizzle (768 blocks, chunk=96). Out fp32 + bo.
// ---------------------------------------------------------------------------
__global__ __launch_bounds__(256) void out_gemm(const unsigned short* __restrict__ Ob,
    const unsigned short* __restrict__ WT, const float* __restrict__ bo,
    float* __restrict__ Out) {
  __shared__ __align__(16) unsigned short As[128 * 32];
  __shared__ __align__(16) unsigned short Bs[128 * 32];
  const unsigned short* Wt = WT + 4 * 65536;
  const int bid  = blockIdx.x;
  const int sbid = (bid & 7) * 96 + (bid >> 3);
  const int bn   = (sbid & 1) * 128;
  const int bm   = (sbid >> 1) * 128;
  const int tid = threadIdx.x;
  const int lane = tid & 63, wid = tid >> 6;
  const int wm = (wid >> 1) * 64, wn = (wid & 1) * 64;
  const int lr = lane & 31, hi = lane >> 5;
  const int srow = lane >> 2, scol = (lane & 3) * 8;

  f32x16 acc[2][2];
#pragma unroll
  for (int i = 0; i < 2; i++)
#pragma unroll
    for (int j = 0; j < 2; j++)
#pragma unroll
      for (int r = 0; r < 16; r++) acc[i][j][r] = 0.f;

  for (int k0 = 0; k0 < 256; k0 += 32) {
#pragma unroll
    for (int i = 0; i < 2; i++) {
      const int rbase = wid * 32 + i * 16;
      gload16(Ob + (size_t)(bm + rbase + srow) * 256 + k0 + scol, &As[rbase * 32]);
      gload16(Wt + (size_t)(bn + rbase + srow) * 256 + k0 + scol, &Bs[rbase * 32]);
    }
    asm volatile("s_waitcnt vmcnt(0)" ::: "memory");
    __syncthreads();
#pragma unroll
    for (int kh = 0; kh < 2; kh++) {
      s16x8 a0 = *(const s16x8*)&As[(wm + lr) * 32      + kh*16 + 8*hi];
      s16x8 a1 = *(const s16x8*)&As[(wm + 32 + lr) * 32 + kh*16 + 8*hi];
      s16x8 b0 = *(const s16x8*)&Bs[(wn + lr) * 32      + kh*16 + 8*hi];
      s16x8 b1 = *(const s16x8*)&Bs[(wn + 32 + lr) * 32 + kh*16 + 8*hi];
      acc[0][0] = MFMA32(a0, b0, acc[0][0]);
      acc[0][1] = MFMA32(a0, b1, acc[0][1]);
      acc[1][0] = MFMA32(a1, b0, acc[1][0]);
      acc[1][1] = MFMA32(a1, b1, acc[1][1]);
    }
    __syncthreads();
  }

#pragma unroll
  for (int ms = 0; ms < 2; ms++) {
#pragma unroll
    for (int ns = 0; ns < 2; ns++) {
      int colg = bn + wn + ns*32 + lr;
      float bov = bo[colg];
#pragma unroll
      for (int r = 0; r < 16; r++) {
        int row = bm + wm + ms*32 + (r & 3) + 8*(r >> 2) + 4*hi;
        Out[(size_t)row * 256 + colg] = acc[ms][ns][r] + bov;
      }
    }
  }
}

// ---------------------------------------------------------------------------
// Host launcher
// ---------------------------------------------------------------------------
extern "C" void kernel_launch(void* const* d_in, const int* in_sizes, int n_in,
                              void* d_out, int out_size, void* d_ws, size_t ws_size,
                              hipStream_t stream) {
  const float* m    = (const float*)d_in[0];
  const float* mask = (const float*)d_in[1];
  const float* ln_w = (const float*)d_in[2];
  const float* ln_b = (const float*)d_in[3];
  const float* wq   = (const float*)d_in[4];
  const float* wk   = (const float*)d_in[5];
  const float* wv   = (const float*)d_in[6];
  const float* wg   = (const float*)d_in[7];
  const float* bg   = (const float*)d_in[8];
  const float* wo   = (const float*)d_in[9];
  const float* bo   = (const float*)d_in[10];
  float* out = (float*)d_out;

  unsigned short* ws = (unsigned short*)d_ws;
  const size_t SZ = (size_t)M_ * 256;
  unsigned short* xbf = ws;
  unsigned short* qb  = ws + 1 * SZ;
  unsigned short* kb  = ws + 2 * SZ;
  unsigned short* vb  = ws + 3 * SZ;
  unsigned short* gb  = ws + 4 * SZ;
  unsigned short* ob  = ws + 5 * SZ;
  unsigned short* WT  = ws + 6 * SZ;

  prep_ln<<<80 + M_ / 4, 256, 0, stream>>>(wq, wk, wv, wg, wo, m, ln_w, ln_b,
                                           WT, xbf);
  proj_gemm<<<3072, 256, 0, stream>>>(xbf, WT, bg, qb, kb, vb, gb);
  attn_kernel<<<dim3(H_, S_), 768, 0, stream>>>(qb, kb, vb, gb, mask, ob);
  out_gemm<<<768, 256, 0, stream>>>(ob, WT, bo, out);
}